// Round 1
// baseline (6889.983 us; speedup 1.0000x reference)
//
#include <hip/hip_runtime.h>
#include <math.h>

#define T_SEQ 120
#define BATCH 256
#define HID   512
#define G3    1536            // 3*HID
#define MROWS (BATCH*T_SEQ)   // 30720
#define TS    (T_SEQ*HID)     // 61440, row stride per batch in out buffers
#define KGATE 122880          // T_SEQ*2*HID

// ---------------------------------------------------------------------------
// build x_in[m=b*120+t][d] = concat(X_lag, X_cov)[t,b,d]
// ---------------------------------------------------------------------------
__global__ void build_x(const float* __restrict__ X_lag,
                        const float* __restrict__ X_cov,
                        float* __restrict__ x_in)
{
    int idx = blockIdx.x * 256 + threadIdx.x;      // < 30720*64
    int d = idx & 63;
    int m = idx >> 6;                               // b*120 + t
    int b = m / 120, t = m - b * 120;
    float v;
    if (d < 32) v = X_lag[((size_t)t * BATCH + b) * 32 + d];
    else        v = X_cov[((size_t)t * BATCH + b) * 32 + (d - 32)];
    x_in[idx] = v;
}

// ---------------------------------------------------------------------------
// Generic tiled f32 GEMM: C[m][n] = bias[n] + sum_k A[m][k] * B[n][k]
// BM=BN=128, KC=32, 256 threads, 8x8 micro-tile. M%128==0, N%128==0, K%32==0.
// ---------------------------------------------------------------------------
__global__ __launch_bounds__(256) void gemm_abt(
    const float* __restrict__ A, const float* __restrict__ B,
    const float* __restrict__ bias, float* __restrict__ C,
    int M, int N, int K)
{
    __shared__ float As[32][129];
    __shared__ float Bs[32][129];
    int m0 = blockIdx.x * 128;
    int n0 = blockIdx.y * 128;
    int tid = threadIdx.x;
    int tx = tid & 15, ty = tid >> 4;
    float acc[8][8] = {};
    for (int k0 = 0; k0 < K; k0 += 32) {
        #pragma unroll
        for (int i = 0; i < 16; i++) {
            int e = tid + i * 256;                 // 0..4095
            int row = e >> 5, col = e & 31;
            As[col][row] = A[(size_t)(m0 + row) * K + k0 + col];
            Bs[col][row] = B[(size_t)(n0 + row) * K + k0 + col];
        }
        __syncthreads();
        #pragma unroll
        for (int kk = 0; kk < 32; kk++) {
            float a[8], b[8];
            #pragma unroll
            for (int i = 0; i < 8; i++) a[i] = As[kk][ty + i * 16];
            #pragma unroll
            for (int j = 0; j < 8; j++) b[j] = Bs[kk][tx + j * 16];
            #pragma unroll
            for (int i = 0; i < 8; i++)
                #pragma unroll
                for (int j = 0; j < 8; j++) acc[i][j] += a[i] * b[j];
        }
        __syncthreads();
    }
    #pragma unroll
    for (int i = 0; i < 8; i++) {
        int m = m0 + ty + i * 16;
        #pragma unroll
        for (int j = 0; j < 8; j++) {
            int n = n0 + tx + j * 16;
            C[(size_t)m * N + n] = acc[i][j] + bias[n];
        }
    }
}

// ---------------------------------------------------------------------------
// One GRU time step (fused gh GEMM + gate nonlinearity).
// out: [256][120][512]; h_prev = out[:, t-1, :] (zeros if t==0), writes out[:, t, :].
// grid (16,16): 16 batch x 32 j per block, 256 threads, 2 outputs/thread.
// ---------------------------------------------------------------------------
__global__ __launch_bounds__(256) void gru_step(
    float* __restrict__ out, const float* __restrict__ gx,
    const float* __restrict__ Whh, const float* __restrict__ bhh, int t)
{
    __shared__ float hs[16][68];
    __shared__ float wsm[3][32][68];
    int b0 = blockIdx.x * 16;
    int j0 = blockIdx.y * 32;
    int tid = threadIdx.x;
    int jt = tid & 15, bt = tid >> 4;
    float ar0 = 0, ar1 = 0, az0 = 0, az1 = 0, an0 = 0, an1 = 0;

    for (int k0 = 0; k0 < 512; k0 += 64) {
        #pragma unroll
        for (int i = 0; i < 4; i++) {               // 16x64 h tile
            int e = tid + i * 256;
            int row = e >> 6, col = e & 63;
            float v = 0.f;
            if (t > 0) v = out[(size_t)(b0 + row) * TS + (size_t)(t - 1) * 512 + k0 + col];
            hs[row][col] = v;
        }
        #pragma unroll
        for (int g = 0; g < 3; g++) {               // 3 x 32x64 W tiles
            #pragma unroll
            for (int i = 0; i < 8; i++) {
                int e = tid + i * 256;
                int row = e >> 6, col = e & 63;
                wsm[g][row][col] = Whh[(size_t)(g * 512 + j0 + row) * 512 + k0 + col];
            }
        }
        __syncthreads();
        #pragma unroll
        for (int kk = 0; kk < 64; kk++) {
            float hv = hs[bt][kk];
            ar0 += hv * wsm[0][jt][kk];
            ar1 += hv * wsm[0][jt + 16][kk];
            az0 += hv * wsm[1][jt][kk];
            az1 += hv * wsm[1][jt + 16][kk];
            an0 += hv * wsm[2][jt][kk];
            an1 += hv * wsm[2][jt + 16][kk];
        }
        __syncthreads();
    }

    int b = b0 + bt;
    size_t gbase = ((size_t)b * T_SEQ + t) * (size_t)G3;
    size_t obase = (size_t)b * TS + (size_t)t * 512;
    size_t pbase = (size_t)b * TS + (size_t)(t - 1) * 512;

    {
        int jc = j0 + jt;
        float r = 1.f / (1.f + expf(-(gx[gbase + jc] + ar0 + bhh[jc])));
        float z = 1.f / (1.f + expf(-(gx[gbase + 512 + jc] + az0 + bhh[512 + jc])));
        float n = tanhf(gx[gbase + 1024 + jc] + r * (an0 + bhh[1024 + jc]));
        float hp = (t > 0) ? out[pbase + jc] : 0.f;
        out[obase + jc] = (1.f - z) * n + z * hp;
    }
    {
        int jc = j0 + jt + 16;
        float r = 1.f / (1.f + expf(-(gx[gbase + jc] + ar1 + bhh[jc])));
        float z = 1.f / (1.f + expf(-(gx[gbase + 512 + jc] + az1 + bhh[512 + jc])));
        float n = tanhf(gx[gbase + 1024 + jc] + r * (an1 + bhh[1024 + jc]));
        float hp = (t > 0) ? out[pbase + jc] : 0.f;
        out[obase + jc] = (1.f - z) * n + z * hp;
    }
}

// ---------------------------------------------------------------------------
// z partials: zp[bk][i][r] = sum_c out[i + half*128][t][c] * Gw[r][t*1024+half*512+c]
// bk = t*2 + half, grid 240 blocks. 256 threads, 8x8 micro-tile (128 i x 128 r-pad).
// ---------------------------------------------------------------------------
__global__ __launch_bounds__(256) void zpart_kernel(
    const float* __restrict__ out, const float* __restrict__ Gw,
    float* __restrict__ zp)
{
    __shared__ float Os[128][33];
    __shared__ float Gs[128][33];
    int bk = blockIdx.x;
    int t = bk >> 1, half = bk & 1;
    int tid = threadIdx.x;
    int tx = tid & 15, ty = tid >> 4;
    float acc[8][8] = {};
    for (int c0 = 0; c0 < 512; c0 += 32) {
        #pragma unroll
        for (int i = 0; i < 16; i++) {
            int e = tid + i * 256;                 // 0..4095
            int row = e >> 5, col = e & 31;
            Os[row][col] = out[(size_t)(row + half * 128) * TS + (size_t)t * 512 + c0 + col];
            float v = 0.f;
            if (row < 120)
                v = Gw[(size_t)row * KGATE + (size_t)t * 1024 + half * 512 + c0 + col];
            Gs[row][col] = v;
        }
        __syncthreads();
        #pragma unroll
        for (int kk = 0; kk < 32; kk++) {
            float a[8], g[8];
            #pragma unroll
            for (int i = 0; i < 8; i++) a[i] = Os[ty + i * 16][kk];
            #pragma unroll
            for (int j = 0; j < 8; j++) g[j] = Gs[tx + j * 16][kk];
            #pragma unroll
            for (int i = 0; i < 8; i++)
                #pragma unroll
                for (int j = 0; j < 8; j++) acc[i][j] += a[i] * g[j];
        }
        __syncthreads();
    }
    float* zb = zp + (size_t)bk * (128 * 120);
    #pragma unroll
    for (int i = 0; i < 8; i++) {
        int ii = ty + i * 16;
        #pragma unroll
        for (int j = 0; j < 8; j++) {
            int r = tx + j * 16;
            if (r < 120) zb[ii * 120 + r] = acc[i][j];
        }
    }
}

// z[i][r] = sum_bk zp[bk][i][r] + gate_b[r]
__global__ void zreduce(const float* __restrict__ zp,
                        const float* __restrict__ gate_b_l,
                        float* __restrict__ z)
{
    int idx = blockIdx.x * 256 + threadIdx.x;      // < 15360
    if (idx >= 128 * 120) return;
    float s = 0.f;
    for (int c = 0; c < 240; c++) s += zp[(size_t)c * (128 * 120) + idx];
    z[idx] = s + gate_b_l[idx % 120];
}

// per-column BN + sigmoid + mean over batch -> wm[r]
__global__ __launch_bounds__(128) void bn_col(
    const float* __restrict__ z, const float* __restrict__ gamma,
    const float* __restrict__ beta, float* __restrict__ wm)
{
    int r = blockIdx.x, i = threadIdx.x;
    __shared__ float sh[2];
    float v = z[i * 120 + r];
    float s = v;
    for (int o = 32; o > 0; o >>= 1) s += __shfl_down(s, o);
    if ((i & 63) == 0) sh[i >> 6] = s;
    __syncthreads();
    float m = (sh[0] + sh[1]) * (1.f / 128.f);
    __syncthreads();
    float d = (v - m) * (v - m);
    for (int o = 32; o > 0; o >>= 1) d += __shfl_down(d, o);
    if ((i & 63) == 0) sh[i >> 6] = d;
    __syncthreads();
    float var = (sh[0] + sh[1]) * (1.f / 128.f);
    float w = 1.f / (1.f + expf(-(gamma[r] * (v - m) / sqrtf(var + 1e-5f) + beta[r])));
    __syncthreads();
    float ws_ = w;
    for (int o = 32; o > 0; o >>= 1) ws_ += __shfl_down(ws_, o);
    if ((i & 63) == 0) sh[i >> 6] = ws_;
    __syncthreads();
    if (i == 0) wm[r] = (sh[0] + sh[1]) * (1.f / 128.f);
}

// softmax over 120 -> write to d_out slot AND ws copy
__global__ __launch_bounds__(128) void softmax120(
    const float* __restrict__ wm, float* __restrict__ g_out,
    float* __restrict__ g_ws)
{
    int i = threadIdx.x;
    __shared__ float sh[2];
    float v = (i < 120) ? wm[i] : -1e30f;
    float m = v;
    for (int o = 32; o > 0; o >>= 1) m = fmaxf(m, __shfl_down(m, o));
    if ((i & 63) == 0) sh[i >> 6] = m;
    __syncthreads();
    float mx = fmaxf(sh[0], sh[1]);
    float e = (i < 120) ? expf(v - mx) : 0.f;
    __syncthreads();
    float se = e;
    for (int o = 32; o > 0; o >>= 1) se += __shfl_down(se, o);
    if ((i & 63) == 0) sh[i >> 6] = se;
    __syncthreads();
    float sum = sh[0] + sh[1];
    if (i < 120) { float g = e / sum; g_out[i] = g; g_ws[i] = g; }
}

// half-batch means: ms[t*512+c] = mean_{i<128} out[i][t][c]; mt likewise for i>=128
__global__ void halfmeans(const float* __restrict__ out,
                          float* __restrict__ ms, float* __restrict__ mt)
{
    int idx = blockIdx.x * 256 + threadIdx.x;      // < 2*61440
    int half = idx >= TS;
    int tc = idx - half * TS;
    const float* base = out + (size_t)(half * 128) * TS + tc;
    float s = 0.f;
    for (int i = 0; i < 128; i++) s += base[(size_t)i * TS];
    s *= (1.f / 128.f);
    if (half) mt[tc] = s; else ms[tc] = s;
}

// per-t masked transfer partial: part[t] = gw[t] * sum_{|t-j|<=lw} ||ms_t - mt_j||^2
__global__ __launch_bounds__(128) void transfer_part(
    const float* __restrict__ ms, const float* __restrict__ mt,
    const float* __restrict__ gw, const int* __restrict__ lenw,
    float* __restrict__ part)
{
    int t = blockIdx.x;
    __shared__ float msh[512];
    for (int i = threadIdx.x; i < 512; i += 128) msh[i] = ms[(size_t)t * 512 + i];
    __syncthreads();
    int j = threadIdx.x;
    int lw = lenw[0];
    float d = 0.f;
    int dd = (t > j) ? (t - j) : (j - t);
    if (j < 120 && dd <= lw) {
        float acc = 0.f;
        for (int c = 0; c < 512; c++) {
            float df = msh[c] - mt[(size_t)j * 512 + c];
            acc += df * df;
        }
        d = acc;
    }
    for (int o = 32; o > 0; o >>= 1) d += __shfl_down(d, o);
    __shared__ float sh[2];
    if ((threadIdx.x & 63) == 0) sh[threadIdx.x >> 6] = d;
    __syncthreads();
    if (threadIdx.x == 0) part[t] = gw[t] * (sh[0] + sh[1]);
}

// prediction head + log-prob partials
__global__ __launch_bounds__(256) void yhat_kernel(
    const float* __restrict__ out1, const float* __restrict__ y,
    const float* __restrict__ fcW, const float* __restrict__ fcb,
    int dsl, float* __restrict__ dout, float* __restrict__ lp_part)
{
    int tt = blockIdx.x;                           // 0..dsl-1
    int b = threadIdx.x;                           // 0..255
    int t = T_SEQ - dsl + tt;
    const float* row = out1 + (size_t)b * TS + (size_t)t * 512;
    float acc = fcb[0];
    for (int c = 0; c < 512; c++) acc += row[c] * fcW[c];
    float loc = acc;
    float sp = fmaxf(loc, 0.f) + log1pf(expf(-fabsf(loc)));
    float scale = sp + 1e-6f;
    dout[2 + tt * 256 + b] = loc;
    dout[2 + dsl * 256 + tt * 256 + b] = scale;
    float yt = y[(size_t)t * 256 + b];
    float u = (yt - loc) / scale;
    float lp = -0.5f * u * u - logf(scale) - 0.91893853320467274f;
    for (int o = 32; o > 0; o >>= 1) lp += __shfl_down(lp, o);
    __shared__ float sh[4];
    if ((threadIdx.x & 63) == 0) sh[threadIdx.x >> 6] = lp;
    __syncthreads();
    if (threadIdx.x == 0) lp_part[tt] = sh[0] + sh[1] + sh[2] + sh[3];
}

// final scalars
__global__ __launch_bounds__(64) void finalize(
    const float* __restrict__ lp_part, const float* __restrict__ part0,
    const float* __restrict__ part1, float* __restrict__ dout, int dsl)
{
    int i = threadIdx.x;
    float s = 0.f;
    for (int k = i; k < dsl; k += 64) s += lp_part[k];
    for (int o = 32; o > 0; o >>= 1) s += __shfl_down(s, o);
    float tr = 0.f;
    for (int k = i; k < 120; k += 64) tr += part0[k] + part1[k];
    for (int o = 32; o > 0; o >>= 1) tr += __shfl_down(tr, o);
    if (i == 0) {
        float ly = -s / (float)(dsl * 256);
        dout[1] = ly;
        dout[0] = ly + tr;
    }
}

// ---------------------------------------------------------------------------
extern "C" void kernel_launch(void* const* d_in, const int* in_sizes, int n_in,
                              void* d_out, int out_size, void* d_ws, size_t ws_size,
                              hipStream_t stream)
{
    const float* X_cov  = (const float*)d_in[1];
    const float* X_lag  = (const float*)d_in[2];
    const float* y      = (const float*)d_in[3];
    const int*   lenw   = (const int*)d_in[5];
    const float* W_ih0  = (const float*)d_in[6];
    const float* W_hh0  = (const float*)d_in[7];
    const float* b_ih0  = (const float*)d_in[8];
    const float* b_hh0  = (const float*)d_in[9];
    const float* W_ih1  = (const float*)d_in[10];
    const float* W_hh1  = (const float*)d_in[11];
    const float* b_ih1  = (const float*)d_in[12];
    const float* b_hh1  = (const float*)d_in[13];
    const float* gate_W = (const float*)d_in[14];
    const float* gate_b = (const float*)d_in[15];
    const float* bn_g   = (const float*)d_in[16];
    const float* bn_b   = (const float*)d_in[17];
    const float* fc_W   = (const float*)d_in[18];
    const float* fc_b   = (const float*)d_in[19];
    float* dout = (float*)d_out;
    float* ws   = (float*)d_ws;

    // workspace layout (floats)
    float* x_in    = ws;                         // 1,966,080
    float* gx      = ws + 1966080;               // 47,185,920
    float* out0    = ws + 49152000;              // 15,728,640
    float* out1    = ws + 64880640;              // 15,728,640
    float* zp      = ws + 80609280;              // 3,686,400
    float* zmat    = ws + 84295680;              // 15,360
    float* wm      = ws + 84311040;              // 120
    float* gw_ws   = ws + 84311160;              // 240
    float* msb     = ws + 84311400;              // 61,440
    float* mtb     = ws + 84372840;               // 61,440
    float* part    = ws + 84434280;              // 240
    float* lp_part = ws + 84434520;              // 24

    int dsl = (out_size - 2 - 2 * T_SEQ) / (2 * BATCH);   // = 24

    build_x<<<dim3(7680), 256, 0, stream>>>(X_lag, X_cov, x_in);
    gemm_abt<<<dim3(240, 12), 256, 0, stream>>>(x_in, W_ih0, b_ih0, gx, MROWS, G3, 64);
    for (int t = 0; t < T_SEQ; t++)
        gru_step<<<dim3(16, 16), 256, 0, stream>>>(out0, gx, W_hh0, b_hh0, t);
    gemm_abt<<<dim3(240, 12), 256, 0, stream>>>(out0, W_ih1, b_ih1, gx, MROWS, G3, 512);
    for (int t = 0; t < T_SEQ; t++)
        gru_step<<<dim3(16, 16), 256, 0, stream>>>(out1, gx, W_hh1, b_hh1, t);

    for (int l = 0; l < 2; l++) {
        const float* o = l ? out1 : out0;
        zpart_kernel<<<240, 256, 0, stream>>>(o, gate_W + (size_t)l * 120 * KGATE, zp);
        zreduce<<<60, 256, 0, stream>>>(zp, gate_b + l * 120, zmat);
        bn_col<<<120, 128, 0, stream>>>(zmat, bn_g + l * 120, bn_b + l * 120, wm);
        softmax120<<<1, 128, 0, stream>>>(wm, dout + 2 + 2 * dsl * 256 + l * 120,
                                          gw_ws + l * 120);
        halfmeans<<<480, 256, 0, stream>>>(o, msb, mtb);
        transfer_part<<<120, 128, 0, stream>>>(msb, mtb, gw_ws + l * 120, lenw,
                                               part + l * 120);
    }

    yhat_kernel<<<dsl, 256, 0, stream>>>(out1, y, fc_W, fc_b, dsl, dout, lp_part);
    finalize<<<1, 64, 0, stream>>>(lp_part, part, part + 120, dout, dsl);
}

// Round 2
// 5050.912 us; speedup vs baseline: 1.3641x; 1.3641x over previous
//
#include <hip/hip_runtime.h>
#include <math.h>

#define T_SEQ 120
#define BATCH 256
#define HID   512
#define G3    1536            // 3*HID
#define MROWS (BATCH*T_SEQ)   // 30720
#define TS    (T_SEQ*HID)     // 61440, row stride per batch in out buffers
#define KGATE 122880          // T_SEQ*2*HID

typedef __attribute__((ext_vector_type(8))) short bf16x8;
typedef __attribute__((ext_vector_type(4))) float f32x4;

__device__ __forceinline__ unsigned short f2bf(float f) {
    union { float f; unsigned u; } x; x.f = f;
    unsigned r = x.u + 0x7fffu + ((x.u >> 16) & 1u);   // RNE
    return (unsigned short)(r >> 16);
}

// ---------------------------------------------------------------------------
// build x_in[m=b*120+t][d] = concat(X_lag, X_cov)[t,b,d]
// ---------------------------------------------------------------------------
__global__ void build_x(const float* __restrict__ X_lag,
                        const float* __restrict__ X_cov,
                        float* __restrict__ x_in)
{
    int idx = blockIdx.x * 256 + threadIdx.x;      // < 30720*64
    int d = idx & 63;
    int m = idx >> 6;                               // b*120 + t
    int b = m / 120, t = m - b * 120;
    float v;
    if (d < 32) v = X_lag[((size_t)t * BATCH + b) * 32 + d];
    else        v = X_cov[((size_t)t * BATCH + b) * 32 + (d - 32)];
    x_in[idx] = v;
}

// cast W_hh0 -> bf16 [1536][512]
__global__ void cast_whh0(const float* __restrict__ W, unsigned short* __restrict__ o)
{
    int i = blockIdx.x * 256 + threadIdx.x;        // < 786432
    o[i] = f2bf(W[i]);
}

// Wcat1 [1536][1024]: cols 0..511 = W_hh1, cols 512..1023 = W_ih1
__global__ void cast_wcat1(const float* __restrict__ Whh, const float* __restrict__ Wih,
                           unsigned short* __restrict__ o)
{
    int i = blockIdx.x * 256 + threadIdx.x;        // < 1572864
    int row = i >> 10, c = i & 1023;
    float v = (c < 512) ? Whh[row * 512 + c] : Wih[row * 512 + (c - 512)];
    o[i] = f2bf(v);
}

// bias_comb0[n] = b_ih0[n] + (n<1024 ? b_hh0[n] : 0);   bc1 likewise for layer 1
__global__ void mkbias(const float* __restrict__ bih0, const float* __restrict__ bhh0,
                       const float* __restrict__ bih1, const float* __restrict__ bhh1,
                       float* __restrict__ bcomb0, float* __restrict__ bc1)
{
    int n = blockIdx.x * 256 + threadIdx.x;        // < 1536
    bcomb0[n] = bih0[n] + (n < 1024 ? bhh0[n] : 0.f);
    bc1[n]    = bih1[n] + (n < 1024 ? bhh1[n] : 0.f);
}

// ---------------------------------------------------------------------------
// Tiled f32 GEMM with TRANSPOSED write for gx0:
// C[(t*256+b)*1536 + n] = bias[n] + sum_k A[m=b*120+t][k]*B[n][k]
// ---------------------------------------------------------------------------
__global__ __launch_bounds__(256) void gemm_abt_t(
    const float* __restrict__ A, const float* __restrict__ B,
    const float* __restrict__ bias, float* __restrict__ C,
    int M, int N, int K)
{
    __shared__ float As[32][129];
    __shared__ float Bs[32][129];
    int m0 = blockIdx.x * 128;
    int n0 = blockIdx.y * 128;
    int tid = threadIdx.x;
    int tx = tid & 15, ty = tid >> 4;
    float acc[8][8] = {};
    for (int k0 = 0; k0 < K; k0 += 32) {
        #pragma unroll
        for (int i = 0; i < 16; i++) {
            int e = tid + i * 256;
            int row = e >> 5, col = e & 31;
            As[col][row] = A[(size_t)(m0 + row) * K + k0 + col];
            Bs[col][row] = B[(size_t)(n0 + row) * K + k0 + col];
        }
        __syncthreads();
        #pragma unroll
        for (int kk = 0; kk < 32; kk++) {
            float a[8], b[8];
            #pragma unroll
            for (int i = 0; i < 8; i++) a[i] = As[kk][ty + i * 16];
            #pragma unroll
            for (int j = 0; j < 8; j++) b[j] = Bs[kk][tx + j * 16];
            #pragma unroll
            for (int i = 0; i < 8; i++)
                #pragma unroll
                for (int j = 0; j < 8; j++) acc[i][j] += a[i] * b[j];
        }
        __syncthreads();
    }
    #pragma unroll
    for (int i = 0; i < 8; i++) {
        int m = m0 + ty + i * 16;
        int b = m / 120, t = m - b * 120;
        #pragma unroll
        for (int j = 0; j < 8; j++) {
            int n = n0 + tx + j * 16;
            C[((size_t)t * 256 + b) * G3 + n] = acc[i][j] + bias[n];
        }
    }
}

// ---------------------------------------------------------------------------
// Pipelined GRU step: launch t runs layer0 step t (blocks 0..31) and
// layer1 step t-1 (blocks 32..63). bf16 MFMA, fragments straight from global.
// Layer1 fuses the Wih1 input GEMM via K-concat ([h1 | x1] @ [Whh1;Wih1]^T).
// ---------------------------------------------------------------------------
__global__ __launch_bounds__(256) void gru_pipe(
    const float* __restrict__ gx0t,                  // [120][256][1536]
    const unsigned short* __restrict__ Whh0,         // [1536][512]
    const unsigned short* __restrict__ Wcat1,        // [1536][1024]
    const float* __restrict__ bhh0,                  // raw b_hh0 [1536]
    const float* __restrict__ bhh1,                  // raw b_hh1 [1536]
    const float* __restrict__ bc1,                   // bih1 + bhh1(r,z) [1536]
    unsigned short* __restrict__ h0bf,               // [2][256][512]
    unsigned short* __restrict__ h1bf,               // [2][256][512]
    float* __restrict__ out0, float* __restrict__ out1,
    int t)
{
    int layer = blockIdx.x >> 5;
    if (!layer && t == T_SEQ) return;
    if (layer && t == 0) return;
    int tau = layer ? t - 1 : t;
    int blk = blockIdx.x & 31;
    int lane = threadIdx.x & 63;
    int w = threadIdx.x >> 6;
    int l15 = lane & 15, l4 = lane >> 4;
    int j = blk * 16 + l15;                          // h column this lane owns
    int bbase = w * 64;

    f32x4 acc0[4], acc1[4], acc2[4], acc3[4];        // r, z, n_h, n_x
    #pragma unroll
    for (int bi = 0; bi < 4; bi++) {
        acc0[bi] = (f32x4){0.f,0.f,0.f,0.f};
        acc1[bi] = (f32x4){0.f,0.f,0.f,0.f};
        acc2[bi] = (f32x4){0.f,0.f,0.f,0.f};
        acc3[bi] = (f32x4){0.f,0.f,0.f,0.f};
    }

    int rp = (tau & 1) ^ 1;                          // parity of h(tau-1)
    const unsigned short* hprev = (layer ? h1bf : h0bf) + (size_t)rp * (256*512);
    const unsigned short* Wb = layer ? Wcat1 : Whh0;
    const int WK = layer ? 1024 : 512;

    // h-part: gh = h(tau-1) @ Whh^T   (gates r,z -> acc0/acc1, n -> acc2)
    if (tau > 0) {
        for (int ks = 0; ks < 16; ks++) {
            int k0 = ks * 32;
            bf16x8 B0 = *(const bf16x8*)(Wb + (size_t)(j)        * WK + k0 + 8*l4);
            bf16x8 B1 = *(const bf16x8*)(Wb + (size_t)(512 + j)  * WK + k0 + 8*l4);
            bf16x8 B2 = *(const bf16x8*)(Wb + (size_t)(1024 + j) * WK + k0 + 8*l4);
            #pragma unroll
            for (int bi = 0; bi < 4; bi++) {
                bf16x8 A = *(const bf16x8*)(hprev + (size_t)(bbase + 16*bi + l15) * 512 + k0 + 8*l4);
                acc0[bi] = __builtin_amdgcn_mfma_f32_16x16x32_bf16(A, B0, acc0[bi], 0,0,0);
                acc1[bi] = __builtin_amdgcn_mfma_f32_16x16x32_bf16(A, B1, acc1[bi], 0,0,0);
                acc2[bi] = __builtin_amdgcn_mfma_f32_16x16x32_bf16(A, B2, acc2[bi], 0,0,0);
            }
        }
    }

    // x-part (layer1 only): gx1 = out0[:,tau,:] @ Wih1^T  (r,z -> acc0/1, n -> acc3)
    if (layer) {
        const unsigned short* hx = h0bf + (size_t)(tau & 1) * (256*512);
        for (int ks = 0; ks < 16; ks++) {
            int k0 = ks * 32;
            bf16x8 B0 = *(const bf16x8*)(Wcat1 + (size_t)(j)        * 1024 + 512 + k0 + 8*l4);
            bf16x8 B1 = *(const bf16x8*)(Wcat1 + (size_t)(512 + j)  * 1024 + 512 + k0 + 8*l4);
            bf16x8 B2 = *(const bf16x8*)(Wcat1 + (size_t)(1024 + j) * 1024 + 512 + k0 + 8*l4);
            #pragma unroll
            for (int bi = 0; bi < 4; bi++) {
                bf16x8 A = *(const bf16x8*)(hx + (size_t)(bbase + 16*bi + l15) * 512 + k0 + 8*l4);
                acc0[bi] = __builtin_amdgcn_mfma_f32_16x16x32_bf16(A, B0, acc0[bi], 0,0,0);
                acc1[bi] = __builtin_amdgcn_mfma_f32_16x16x32_bf16(A, B1, acc1[bi], 0,0,0);
                acc3[bi] = __builtin_amdgcn_mfma_f32_16x16x32_bf16(A, B2, acc3[bi], 0,0,0);
            }
        }
    }

    // epilogue: gates + state update. C/D layout: col=lane&15, row=(lane>>4)*4+reg.
    float bn  = layer ? bhh1[1024 + j] : bhh0[1024 + j];
    float bcr = 0.f, bcz = 0.f, bcn = 0.f;
    if (layer) { bcr = bc1[j]; bcz = bc1[512 + j]; bcn = bc1[1024 + j]; }
    unsigned short* hw = (layer ? h1bf : h0bf) + (size_t)(tau & 1) * (256*512);
    float* outp = layer ? out1 : out0;

    #pragma unroll
    for (int bi = 0; bi < 4; bi++) {
        #pragma unroll
        for (int rr = 0; rr < 4; rr++) {
            int b = bbase + 16*bi + 4*l4 + rr;
            float pr, pz, pnx;
            if (!layer) {
                const float* gp = gx0t + ((size_t)tau * 256 + b) * G3 + j;
                pr  = gp[0]    + acc0[bi][rr];
                pz  = gp[512]  + acc1[bi][rr];
                pnx = gp[1024];
            } else {
                pr  = acc0[bi][rr] + bcr;
                pz  = acc1[bi][rr] + bcz;
                pnx = acc3[bi][rr] + bcn;
            }
            float r = 1.f / (1.f + expf(-pr));
            float z = 1.f / (1.f + expf(-pz));
            float n = tanhf(pnx + r * (acc2[bi][rr] + bn));
            float hp = (tau > 0) ? outp[(size_t)b * TS + (size_t)(tau - 1) * 512 + j] : 0.f;
            float h = (1.f - z) * n + z * hp;
            outp[(size_t)b * TS + (size_t)tau * 512 + j] = h;
            hw[(size_t)b * 512 + j] = f2bf(h);
        }
    }
}

// ---------------------------------------------------------------------------
// z partials (unchanged)
// ---------------------------------------------------------------------------
__global__ __launch_bounds__(256) void zpart_kernel(
    const float* __restrict__ out, const float* __restrict__ Gw,
    float* __restrict__ zp)
{
    __shared__ float Os[128][33];
    __shared__ float Gs[128][33];
    int bk = blockIdx.x;
    int t = bk >> 1, half = bk & 1;
    int tid = threadIdx.x;
    int tx = tid & 15, ty = tid >> 4;
    float acc[8][8] = {};
    for (int c0 = 0; c0 < 512; c0 += 32) {
        #pragma unroll
        for (int i = 0; i < 16; i++) {
            int e = tid + i * 256;
            int row = e >> 5, col = e & 31;
            Os[row][col] = out[(size_t)(row + half * 128) * TS + (size_t)t * 512 + c0 + col];
            float v = 0.f;
            if (row < 120)
                v = Gw[(size_t)row * KGATE + (size_t)t * 1024 + half * 512 + c0 + col];
            Gs[row][col] = v;
        }
        __syncthreads();
        #pragma unroll
        for (int kk = 0; kk < 32; kk++) {
            float a[8], g[8];
            #pragma unroll
            for (int i = 0; i < 8; i++) a[i] = Os[ty + i * 16][kk];
            #pragma unroll
            for (int j = 0; j < 8; j++) g[j] = Gs[tx + j * 16][kk];
            #pragma unroll
            for (int i = 0; i < 8; i++)
                #pragma unroll
                for (int j = 0; j < 8; j++) acc[i][j] += a[i] * g[j];
        }
        __syncthreads();
    }
    float* zb = zp + (size_t)bk * (128 * 120);
    #pragma unroll
    for (int i = 0; i < 8; i++) {
        int ii = ty + i * 16;
        #pragma unroll
        for (int j = 0; j < 8; j++) {
            int r = tx + j * 16;
            if (r < 120) zb[ii * 120 + r] = acc[i][j];
        }
    }
}

__global__ void zreduce(const float* __restrict__ zp,
                        const float* __restrict__ gate_b_l,
                        float* __restrict__ z)
{
    int idx = blockIdx.x * 256 + threadIdx.x;
    if (idx >= 128 * 120) return;
    float s = 0.f;
    for (int c = 0; c < 240; c++) s += zp[(size_t)c * (128 * 120) + idx];
    z[idx] = s + gate_b_l[idx % 120];
}

__global__ __launch_bounds__(128) void bn_col(
    const float* __restrict__ z, const float* __restrict__ gamma,
    const float* __restrict__ beta, float* __restrict__ wm)
{
    int r = blockIdx.x, i = threadIdx.x;
    __shared__ float sh[2];
    float v = z[i * 120 + r];
    float s = v;
    for (int o = 32; o > 0; o >>= 1) s += __shfl_down(s, o);
    if ((i & 63) == 0) sh[i >> 6] = s;
    __syncthreads();
    float m = (sh[0] + sh[1]) * (1.f / 128.f);
    __syncthreads();
    float d = (v - m) * (v - m);
    for (int o = 32; o > 0; o >>= 1) d += __shfl_down(d, o);
    if ((i & 63) == 0) sh[i >> 6] = d;
    __syncthreads();
    float var = (sh[0] + sh[1]) * (1.f / 128.f);
    float w = 1.f / (1.f + expf(-(gamma[r] * (v - m) / sqrtf(var + 1e-5f) + beta[r])));
    __syncthreads();
    float ws_ = w;
    for (int o = 32; o > 0; o >>= 1) ws_ += __shfl_down(ws_, o);
    if ((i & 63) == 0) sh[i >> 6] = ws_;
    __syncthreads();
    if (i == 0) wm[r] = (sh[0] + sh[1]) * (1.f / 128.f);
}

__global__ __launch_bounds__(128) void softmax120(
    const float* __restrict__ wm, float* __restrict__ g_out,
    float* __restrict__ g_ws)
{
    int i = threadIdx.x;
    __shared__ float sh[2];
    float v = (i < 120) ? wm[i] : -1e30f;
    float m = v;
    for (int o = 32; o > 0; o >>= 1) m = fmaxf(m, __shfl_down(m, o));
    if ((i & 63) == 0) sh[i >> 6] = m;
    __syncthreads();
    float mx = fmaxf(sh[0], sh[1]);
    float e = (i < 120) ? expf(v - mx) : 0.f;
    __syncthreads();
    float se = e;
    for (int o = 32; o > 0; o >>= 1) se += __shfl_down(se, o);
    if ((i & 63) == 0) sh[i >> 6] = se;
    __syncthreads();
    float sum = sh[0] + sh[1];
    if (i < 120) { float g = e / sum; g_out[i] = g; g_ws[i] = g; }
}

__global__ void halfmeans(const float* __restrict__ out,
                          float* __restrict__ ms, float* __restrict__ mt)
{
    int idx = blockIdx.x * 256 + threadIdx.x;
    int half = idx >= TS;
    int tc = idx - half * TS;
    const float* base = out + (size_t)(half * 128) * TS + tc;
    float s = 0.f;
    for (int i = 0; i < 128; i++) s += base[(size_t)i * TS];
    s *= (1.f / 128.f);
    if (half) mt[tc] = s; else ms[tc] = s;
}

__global__ __launch_bounds__(128) void transfer_part(
    const float* __restrict__ ms, const float* __restrict__ mt,
    const float* __restrict__ gw, const int* __restrict__ lenw,
    float* __restrict__ part)
{
    int t = blockIdx.x;
    __shared__ float msh[512];
    for (int i = threadIdx.x; i < 512; i += 128) msh[i] = ms[(size_t)t * 512 + i];
    __syncthreads();
    int j = threadIdx.x;
    int lw = lenw[0];
    float d = 0.f;
    int dd = (t > j) ? (t - j) : (j - t);
    if (j < 120 && dd <= lw) {
        float acc = 0.f;
        for (int c = 0; c < 512; c++) {
            float df = msh[c] - mt[(size_t)j * 512 + c];
            acc += df * df;
        }
        d = acc;
    }
    for (int o = 32; o > 0; o >>= 1) d += __shfl_down(d, o);
    __shared__ float sh[2];
    if ((threadIdx.x & 63) == 0) sh[threadIdx.x >> 6] = d;
    __syncthreads();
    if (threadIdx.x == 0) part[t] = gw[t] * (sh[0] + sh[1]);
}

__global__ __launch_bounds__(256) void yhat_kernel(
    const float* __restrict__ out1, const float* __restrict__ y,
    const float* __restrict__ fcW, const float* __restrict__ fcb,
    int dsl, float* __restrict__ dout, float* __restrict__ lp_part)
{
    int tt = blockIdx.x;
    int b = threadIdx.x;
    int t = T_SEQ - dsl + tt;
    const float* row = out1 + (size_t)b * TS + (size_t)t * 512;
    float acc = fcb[0];
    for (int c = 0; c < 512; c++) acc += row[c] * fcW[c];
    float loc = acc;
    float sp = fmaxf(loc, 0.f) + log1pf(expf(-fabsf(loc)));
    float scale = sp + 1e-6f;
    dout[2 + tt * 256 + b] = loc;
    dout[2 + dsl * 256 + tt * 256 + b] = scale;
    float yt = y[(size_t)t * 256 + b];
    float u = (yt - loc) / scale;
    float lp = -0.5f * u * u - logf(scale) - 0.91893853320467274f;
    for (int o = 32; o > 0; o >>= 1) lp += __shfl_down(lp, o);
    __shared__ float sh[4];
    if ((threadIdx.x & 63) == 0) sh[threadIdx.x >> 6] = lp;
    __syncthreads();
    if (threadIdx.x == 0) lp_part[tt] = sh[0] + sh[1] + sh[2] + sh[3];
}

__global__ __launch_bounds__(64) void finalize(
    const float* __restrict__ lp_part, const float* __restrict__ part0,
    const float* __restrict__ part1, float* __restrict__ dout, int dsl)
{
    int i = threadIdx.x;
    float s = 0.f;
    for (int k = i; k < dsl; k += 64) s += lp_part[k];
    for (int o = 32; o > 0; o >>= 1) s += __shfl_down(s, o);
    float tr = 0.f;
    for (int k = i; k < 120; k += 64) tr += part0[k] + part1[k];
    for (int o = 32; o > 0; o >>= 1) tr += __shfl_down(tr, o);
    if (i == 0) {
        float ly = -s / (float)(dsl * 256);
        dout[1] = ly;
        dout[0] = ly + tr;
    }
}

// ---------------------------------------------------------------------------
extern "C" void kernel_launch(void* const* d_in, const int* in_sizes, int n_in,
                              void* d_out, int out_size, void* d_ws, size_t ws_size,
                              hipStream_t stream)
{
    const float* X_cov  = (const float*)d_in[1];
    const float* X_lag  = (const float*)d_in[2];
    const float* y      = (const float*)d_in[3];
    const int*   lenw   = (const int*)d_in[5];
    const float* W_ih0  = (const float*)d_in[6];
    const float* W_hh0  = (const float*)d_in[7];
    const float* b_ih0  = (const float*)d_in[8];
    const float* b_hh0  = (const float*)d_in[9];
    const float* W_ih1  = (const float*)d_in[10];
    const float* W_hh1  = (const float*)d_in[11];
    const float* b_ih1  = (const float*)d_in[12];
    const float* b_hh1  = (const float*)d_in[13];
    const float* gate_W = (const float*)d_in[14];
    const float* gate_b = (const float*)d_in[15];
    const float* bn_g   = (const float*)d_in[16];
    const float* bn_b   = (const float*)d_in[17];
    const float* fc_W   = (const float*)d_in[18];
    const float* fc_b   = (const float*)d_in[19];
    float* dout = (float*)d_out;
    float* ws   = (float*)d_ws;

    // workspace layout (float offsets). bf16 buffers overlap the zp region —
    // they are dead before zpart_kernel runs (time-disjoint, re-written each call).
    float* x_in    = ws;                         // 1,966,080
    float* gx0t    = ws + 1966080;               // 47,185,920  [120][256][1536]
    float* out0    = ws + 49152000;              // 15,728,640
    float* out1    = ws + 64880640;              // 15,728,640
    float* zp      = ws + 80609280;              // 3,686,400
    unsigned short* Whh0bf  = (unsigned short*)(ws + 80609280);  // 786,432 ush
    unsigned short* Wcat1bf = (unsigned short*)(ws + 81002496);  // 1,572,864 ush
    unsigned short* h0bf    = (unsigned short*)(ws + 81788928);  // 2*256*512 ush
    unsigned short* h1bf    = (unsigned short*)(ws + 81920000);  // 2*256*512 ush
    float* zmat    = ws + 84295680;              // 15,360
    float* wm      = ws + 84311040;              // 120
    float* gw_ws   = ws + 84311160;              // 240
    float* msb     = ws + 84311400;              // 61,440
    float* mtb     = ws + 84372840;              // 61,440
    float* part    = ws + 84434280;              // 240
    float* lp_part = ws + 84434520;              // 24
    float* bcomb0  = ws + 84434560;              // 1536
    float* bc1     = ws + 84436096;              // 1536

    int dsl = (out_size - 2 - 2 * T_SEQ) / (2 * BATCH);   // = 24

    build_x<<<dim3(7680), 256, 0, stream>>>(X_lag, X_cov, x_in);
    cast_whh0<<<dim3(3072), 256, 0, stream>>>(W_hh0, Whh0bf);
    cast_wcat1<<<dim3(6144), 256, 0, stream>>>(W_hh1, W_ih1, Wcat1bf);
    mkbias<<<dim3(6), 256, 0, stream>>>(b_ih0, b_hh0, b_ih1, b_hh1, bcomb0, bc1);

    gemm_abt_t<<<dim3(240, 12), 256, 0, stream>>>(x_in, W_ih0, bcomb0, gx0t,
                                                  MROWS, G3, 64);

    for (int t = 0; t <= T_SEQ; t++)
        gru_pipe<<<dim3(64), 256, 0, stream>>>(gx0t, Whh0bf, Wcat1bf,
                                               b_hh0, b_hh1, bc1,
                                               h0bf, h1bf, out0, out1, t);

    for (int l = 0; l < 2; l++) {
        const float* o = l ? out1 : out0;
        zpart_kernel<<<240, 256, 0, stream>>>(o, gate_W + (size_t)l * 120 * KGATE, zp);
        zreduce<<<60, 256, 0, stream>>>(zp, gate_b + l * 120, zmat);
        bn_col<<<120, 128, 0, stream>>>(zmat, bn_g + l * 120, bn_b + l * 120, wm);
        softmax120<<<1, 128, 0, stream>>>(wm, dout + 2 + 2 * dsl * 256 + l * 120,
                                          gw_ws + l * 120);
        halfmeans<<<480, 256, 0, stream>>>(o, msb, mtb);
        transfer_part<<<120, 128, 0, stream>>>(msb, mtb, gw_ws + l * 120, lenw,
                                               part + l * 120);
    }

    yhat_kernel<<<dsl, 256, 0, stream>>>(out1, y, fc_W, fc_b, dsl, dout, lp_part);
    finalize<<<1, 64, 0, stream>>>(lp_part, part, part + 120, dout, dsl);
}